// Round 5
// baseline (345.278 us; speedup 1.0000x reference)
//
#include <hip/hip_runtime.h>
#include <cstddef>
#include <cstdint>

#define SEQ    2048
#define DMODEL 1024
#define NHEAD  16
#define HDIM   64
#define SCALE  0.125f

typedef _Float16 f16;
typedef unsigned short u16;
typedef unsigned int   u32;
typedef __attribute__((ext_vector_type(8))) _Float16 h8v;
typedef __attribute__((ext_vector_type(4))) _Float16 h4v;
typedef __attribute__((ext_vector_type(4))) float    f4v;

__device__ __forceinline__ u32 pkh(float a, float b) {
    u16 x = __builtin_bit_cast(u16, (f16)a);
    u16 y = __builtin_bit_cast(u16, (f16)b);
    return (u32)x | ((u32)y << 16);
}

__device__ __forceinline__ f4v mfma32(h8v a, h8v b, f4v c) {
    return __builtin_amdgcn_mfma_f32_16x16x32_f16(a, b, c, 0, 0, 0);
}
__device__ __forceinline__ f4v mfma16(h4v a, h4v b, f4v c) {
    return __builtin_amdgcn_mfma_f32_16x16x16f16(a, b, c, 0, 0, 0);
}

// ---------------------------------------------------------------------------
// Convert x, Wqkv, Wout (fp32) -> f16 row-major copies.
// ---------------------------------------------------------------------------
__global__ __launch_bounds__(256)
void cvt_f16_kernel(const float* __restrict__ x, const float* __restrict__ Wqkv,
                    const float* __restrict__ Wout,
                    f16* __restrict__ Xh, f16* __restrict__ Wqh, f16* __restrict__ Woh)
{
    size_t i = ((size_t)blockIdx.x * 256 + threadIdx.x) * 8;
    const float* src; f16* dst; size_t off;
    if (i < 4194304)      { src = x;    dst = Xh;  off = i; }
    else if (i < 7340032) { src = Wqkv; dst = Wqh; off = i - 4194304; }
    else                  { src = Wout; dst = Woh; off = i - 7340032; }
    float4 a = *(const float4*)&src[off];
    float4 b = *(const float4*)&src[off + 4];
    uint4 o;
    o.x = pkh(a.x, a.y); o.y = pkh(a.z, a.w);
    o.z = pkh(b.x, b.y); o.w = pkh(b.z, b.w);
    *(uint4*)&dst[off] = o;
}

// ---------------------------------------------------------------------------
// f16 MFMA GEMM: C = A @ B^T + bias. 128x128 tile, BK=32, 4 waves.
// mode 0: store f16. mode 1: store fp32.
// ---------------------------------------------------------------------------
__global__ __launch_bounds__(256)
void gemm_f16_kernel(const f16* __restrict__ A, const f16* __restrict__ B,
                     const float* __restrict__ bias, void* __restrict__ Cout,
                     int N, int K, int mode)
{
    __shared__ __align__(16) char Asb[8192];
    __shared__ __align__(16) char Bsb[8192];
    int tid = threadIdx.x;
    int w = tid >> 6, l = tid & 63, lr = l & 15, lc = l >> 4;
    int row0 = blockIdx.y * 128, col0 = blockIdx.x * 128;
    int wr = (w >> 1) * 64, wc = (w & 1) * 64;

    f4v acc[4][4];
    #pragma unroll
    for (int m = 0; m < 4; ++m)
        #pragma unroll
        for (int n = 0; n < 4; ++n) acc[m][n] = (f4v){0.f, 0.f, 0.f, 0.f};

    int r0 = tid >> 2, k0s = tid & 3;
    int r1 = (tid + 256) >> 2, k1s = tid & 3;

    uint4 ra0, ra1, rb0, rb1;
    ra0 = *(const uint4*)&A[(size_t)(row0 + r0) * K + k0s * 8];
    ra1 = *(const uint4*)&A[(size_t)(row0 + r1) * K + k1s * 8];
    rb0 = *(const uint4*)&B[(size_t)(col0 + r0) * K + k0s * 8];
    rb1 = *(const uint4*)&B[(size_t)(col0 + r1) * K + k1s * 8];

    int NT = K >> 5;
    for (int kt = 0; kt < NT; ++kt) {
        *(uint4*)(Asb + r0 * 64 + ((k0s ^ (r0 & 3)) << 4)) = ra0;
        *(uint4*)(Asb + r1 * 64 + ((k1s ^ (r1 & 3)) << 4)) = ra1;
        *(uint4*)(Bsb + r0 * 64 + ((k0s ^ (r0 & 3)) << 4)) = rb0;
        *(uint4*)(Bsb + r1 * 64 + ((k1s ^ (r1 & 3)) << 4)) = rb1;
        if (kt + 1 < NT) {
            int kk = (kt + 1) * 32;
            ra0 = *(const uint4*)&A[(size_t)(row0 + r0) * K + kk + k0s * 8];
            ra1 = *(const uint4*)&A[(size_t)(row0 + r1) * K + kk + k1s * 8];
            rb0 = *(const uint4*)&B[(size_t)(col0 + r0) * K + kk + k0s * 8];
            rb1 = *(const uint4*)&B[(size_t)(col0 + r1) * K + kk + k1s * 8];
        }
        __syncthreads();
        h8v af[4], bf[4];
        #pragma unroll
        for (int m = 0; m < 4; ++m) {
            int row = wr + m * 16 + lr;
            af[m] = *(h8v*)(Asb + row * 64 + ((lc ^ (row & 3)) << 4));
        }
        #pragma unroll
        for (int n = 0; n < 4; ++n) {
            int col = wc + n * 16 + lr;
            bf[n] = *(h8v*)(Bsb + col * 64 + ((lc ^ (col & 3)) << 4));
        }
        #pragma unroll
        for (int m = 0; m < 4; ++m)
            #pragma unroll
            for (int n = 0; n < 4; ++n)
                acc[m][n] = mfma32(af[m], bf[n], acc[m][n]);
        __syncthreads();
    }

    #pragma unroll
    for (int m = 0; m < 4; ++m)
        #pragma unroll
        for (int r = 0; r < 4; ++r) {
            int row = row0 + wr + m * 16 + lc * 4 + r;
            #pragma unroll
            for (int n = 0; n < 4; ++n) {
                int col = col0 + wc + n * 16 + lr;
                float v = acc[m][n][r] + bias[col];
                if (mode == 0) ((f16*)Cout)[(size_t)row * N + col] = (f16)v;
                else           ((float*)Cout)[(size_t)row * N + col] = v;
            }
        }
}

// ---------------------------------------------------------------------------
// Pack Q,K (with RoPE) from f16 QKV [row][3072] into f16 MFMA frag layout.
// ---------------------------------------------------------------------------
__global__ __launch_bounds__(256)
void pack_qk_kernel(const f16* __restrict__ QKVh, f16* __restrict__ Qh, f16* __restrict__ Kh)
{
    int gid = blockIdx.x * 256 + threadIdx.x;
    int i     = gid & 15;
    int t8    = (gid >> 4) & 3;
    int h     = (gid >> 6) & 15;
    int rh    = (gid >> 10) & 255;
    int which = (gid >> 18) & 1;
    int row = rh * 16 + i;
    int pos = row & (SEQ - 1);
    int b   = row >> 11;
    f16* dst = which ? Kh : Qh;

    h8v x1 = *(const h8v*)&QKVh[(size_t)row * 3072 + which * 1024 + h * 64 + t8 * 8];
    h8v x2 = *(const h8v*)&QKVh[(size_t)row * 3072 + which * 1024 + h * 64 + t8 * 8 + 32];

    float y1[8], y2[8];
    #pragma unroll
    for (int e = 0; e < 8; ++e) {
        int t = t8 * 8 + e;
        float inv = exp2f((float)(-2 * t) * (0.015625f * 13.287712379549449f));
        float ang = (float)pos * inv;
        float c, s;
        sincosf(ang, &s, &c);
        float a1 = (float)x1[e], a2 = (float)x2[e];
        y1[e] = a1 * c - a2 * s;
        y2[e] = a1 * s + a2 * c;
    }
    int it = pos >> 4;
    size_t b0 = (((((size_t)(b*128 + it)*16 + h)*2 + 0)*4 + t8)*16 + i)*8;
    size_t b1 = (((((size_t)(b*128 + it)*16 + h)*2 + 1)*4 + t8)*16 + i)*8;
    uint4 o0, o1;
    o0.x = pkh(y1[0], y1[1]); o0.y = pkh(y1[2], y1[3]);
    o0.z = pkh(y1[4], y1[5]); o0.w = pkh(y1[6], y1[7]);
    o1.x = pkh(y2[0], y2[1]); o1.y = pkh(y2[2], y2[3]);
    o1.z = pkh(y2[4], y2[5]); o1.w = pkh(y2[6], y2[7]);
    *(uint4*)(dst + b0) = o0;
    *(uint4*)(dst + b1) = o1;
}

// ---------------------------------------------------------------------------
// Pack V from f16 QKV [row][3072] (cols 2048..3071) into PV B-frag layout.
// ---------------------------------------------------------------------------
__global__ __launch_bounds__(256)
void pack_v_kernel(const f16* __restrict__ QKVh, f16* __restrict__ Vt)
{
    int gid = blockIdx.x * 256 + threadIdx.x;
    int dd = gid & 15;
    int jc = (gid >> 4) & 3;
    int dt = (gid >> 6) & 3;
    int g  = (gid >> 8) & 15;
    int jt = (gid >> 12) & 63;
    int b  = (gid >> 18) & 1;
    int d = g * 64 + dt * 16 + dd;
    f16 v[8];
    #pragma unroll
    for (int e = 0; e < 8; ++e) {
        int j = jt * 32 + jc * 8 + e;
        v[e] = QKVh[(size_t)(b * SEQ + j) * 3072 + 2048 + d];
    }
    size_t off = ((((((size_t)b*64 + jt)*16 + g)*4 + dt)*4 + jc)*16 + dd)*8;
    uint4 o;
    o.x = pkh((float)v[0], (float)v[1]); o.y = pkh((float)v[2], (float)v[3]);
    o.z = pkh((float)v[4], (float)v[5]); o.w = pkh((float)v[6], (float)v[7]);
    *(uint4*)(Vt + off) = o;
}

// ---------------------------------------------------------------------------
// Sum 4 f16 attention split partials -> f16 CTX [4096][1024].
// ---------------------------------------------------------------------------
__global__ __launch_bounds__(256)
void pack_ctx_kernel(const f16* __restrict__ Cp, f16* __restrict__ Ch)
{
    size_t i = ((size_t)blockIdx.x * 256 + threadIdx.x) * 8;
    h8v p0 = *(const h8v*)&Cp[i];
    h8v p1 = *(const h8v*)&Cp[i + 4194304];
    h8v p2 = *(const h8v*)&Cp[i + 8388608];
    h8v p3 = *(const h8v*)&Cp[i + 12582912];
    float s[8];
    #pragma unroll
    for (int e = 0; e < 8; ++e)
        s[e] = (float)p0[e] + (float)p1[e] + (float)p2[e] + (float)p3[e];
    uint4 o;
    o.x = pkh(s[0], s[1]); o.y = pkh(s[2], s[3]);
    o.z = pkh(s[4], s[5]); o.w = pkh(s[6], s[7]);
    *(uint4*)&Ch[i] = o;
}

// ---------------------------------------------------------------------------
// MFMA talking-heads attention core.
// FULL=0: pass 1 -> Z partials. FULL=1: pass 2 -> f16 CTX partials.
// Grid 1024: bid = it*8 + group; group = (split<<1)|b  (XCD-locality: all 128
// it-blocks of one (split,b) land on one XCD; K+V working set 2MB < 4MB L2).
// S0 LDS: region (hs,js) 2KB each; addr = i*128 + (j'^i)*8; hs holds heads
// hs*4..+3 packed 4xf16 per point. Write: 16 bank-pairs x 4 lanes; read same.
// ---------------------------------------------------------------------------
template<int FULL>
__global__ __launch_bounds__(256, 4)
void attn_core(const f16* __restrict__ Qh, const f16* __restrict__ Kh,
               const f16* __restrict__ Vt, const float* __restrict__ Wpre,
               const float* __restrict__ Wpost, const float* __restrict__ Zp,
               float* __restrict__ Zout, f16* __restrict__ Octx)
{
    __shared__ __align__(16) char ss[16384];                 // S0 [hs][js][i][j'^i] f16x4
    __shared__ __align__(16) char es[FULL ? 16 * 1024 : 16]; // f16 A2 [g'][i][j32]
    __shared__ float zred[FULL ? 256 : 1024];

    int tid = threadIdx.x;
    int wv = tid >> 6;
    int l  = tid & 63;
    int lr = l & 15;
    int lc = l >> 4;

    int bid   = blockIdx.x;
    int group = bid & 7;
    int it    = bid >> 3;
    int b     = group & 1;
    int split = group >> 1;

    // Wpre fragment (A of 16x16x16): row g' = lr, k(h) = lc*4+e
    h4v wpre4;
    #pragma unroll
    for (int e = 0; e < 4; ++e) wpre4[e] = (f16)(Wpre[lr * 16 + lc * 4 + e] * SCALE);
    h4v wpost;
    if (FULL) {
        #pragma unroll
        for (int e = 0; e < 4; ++e) wpost[e] = (f16)Wpost[lr * 16 + lc * 4 + e];
    }

    // Q fragments: wave's heads 4wv..4wv+3, rows it*16..+15
    h8v qf[4][2];
    #pragma unroll
    for (int hh = 0; hh < 4; ++hh)
        #pragma unroll
        for (int ks = 0; ks < 2; ++ks) {
            size_t off = ((((size_t)((b*128 + it)*16 + (wv*4 + hh))*2 + ks)*4 + lc)*16 + lr)*8;
            qf[hh][ks] = *(const h8v*)(Qh + off);
        }

    float zin4[4];
    float zacc[4] = {0.f, 0.f, 0.f, 0.f};
    if (FULL) {
        int g = tid >> 4, i = tid & 15;
        size_t idx = (size_t)(b * 16 + g) * SEQ + it * 16 + i;
        zred[tid] = 1.0f / (Zp[idx] + Zp[65536 + idx] + Zp[131072 + idx] + Zp[196608 + idx]);
        __syncthreads();
        #pragma unroll
        for (int r = 0; r < 4; ++r) zin4[r] = zred[(lc * 4 + r) * 16 + lr];
    }

    f4v pv[4][4];
    if (FULL) {
        #pragma unroll
        for (int gg = 0; gg < 4; ++gg)
            #pragma unroll
            for (int dt = 0; dt < 4; ++dt) pv[gg][dt] = (f4v){0.f, 0.f, 0.f, 0.f};
    }

    int j0beg = split * 512;
    for (int j0 = j0beg; j0 < j0beg + 512; j0 += 32) {
        // ---- phase 1: QK^T for wave's 4 heads ----
        f4v qk[4][2];
        #pragma unroll
        for (int hh = 0; hh < 4; ++hh)
            #pragma unroll
            for (int js = 0; js < 2; ++js) qk[hh][js] = (f4v){0.f, 0.f, 0.f, 0.f};
        int jt0 = j0 >> 4;
        #pragma unroll
        for (int hh = 0; hh < 4; ++hh) {
            h8v kf[2][2];
            #pragma unroll
            for (int js = 0; js < 2; ++js)
                #pragma unroll
                for (int ks = 0; ks < 2; ++ks) {
                    size_t off = ((((size_t)((b*128 + jt0 + js)*16 + (wv*4 + hh))*2 + ks)*4 + lc)*16 + lr)*8;
                    kf[js][ks] = *(const h8v*)(Kh + off);
                }
            #pragma unroll
            for (int js = 0; js < 2; ++js)
                #pragma unroll
                for (int ks = 0; ks < 2; ++ks)
                    qk[hh][js] = mfma32(qf[hh][ks], kf[js][ks], qk[hh][js]);
        }
        // S0 -> ss: wave wv = region hs (its 4 heads per 8B point)
        #pragma unroll
        for (int js = 0; js < 2; ++js)
            #pragma unroll
            for (int r = 0; r < 4; ++r) {
                int i = lc * 4 + r;
                int addr = (wv * 2 + js) * 2048 + i * 128 + ((lr ^ i) << 3);
                u32 lo = pkh(qk[0][js][r], qk[1][js][r]);
                u32 hi = pkh(qk[2][js][r], qk[3][js][r]);
                *(uint2*)(ss + addr) = make_uint2(lo, hi);
            }
        __syncthreads();

        // ---- phase 2: premix (K=16) -> exp -> (Z accum | x1/Z -> postmix -> es) ----
        u32 a2p[4][4];
        #pragma unroll
        for (int tt = 0; tt < 8; ++tt) {
            int t = wv * 8 + tt;            // j within step
            int addr = (lc * 2 + (t >> 4)) * 2048 + lr * 128 + (((t & 15) ^ lr) << 3);
            union { uint2 u; h4v v; } cv;
            cv.u = *(uint2*)(ss + addr);
            f4v s1 = mfma16(wpre4, cv.v, (f4v){0.f, 0.f, 0.f, 0.f});
            if (!FULL) {
                #pragma unroll
                for (int r = 0; r < 4; ++r) zacc[r] += __expf(s1[r]);
            } else {
                h4v pf;
                #pragma unroll
                for (int r = 0; r < 4; ++r) pf[r] = (f16)(__expf(s1[r]) * zin4[r]);
                f4v a2 = mfma16(wpost, pf, (f4v){0.f, 0.f, 0.f, 0.f});
                #pragma unroll
                for (int r = 0; r < 4; ++r) {
                    u32 v = (u32)__builtin_bit_cast(u16, (f16)a2[r]);
                    if (tt & 1) a2p[r][tt >> 1] |= v << 16;
                    else        a2p[r][tt >> 1]  = v;
                }
            }
        }
        if (FULL) {
            #pragma unroll
            for (int r = 0; r < 4; ++r) {
                int gq = lc * 4 + r;
                int off = (gq * 1024 + lr * 64 + wv * 16) ^ ((lr & 7) << 4);
                *(uint4*)(es + off) = make_uint4(a2p[r][0], a2p[r][1], a2p[r][2], a2p[r][3]);
            }
        }
        __syncthreads();

        // ---- phase 3: PV for wave's 4 output heads ----
        if (FULL) {
            #pragma unroll
            for (int gg = 0; gg < 4; ++gg) {
                int g = wv * 4 + gg;
                h8v af = *(h8v*)(es + ((g * 1024 + lr * 64 + lc * 16) ^ ((lr & 7) << 4)));
                #pragma unroll
                for (int dt = 0; dt < 4; ++dt) {
                    size_t voff = (((((size_t)(b*64 + (j0 >> 5))*16 + g)*4 + dt)*4 + lc)*16 + lr)*8;
                    h8v vf = *(const h8v*)(Vt + voff);
                    pv[gg][dt] = mfma32(af, vf, pv[gg][dt]);
                }
            }
        }
    }

    if (!FULL) {
        #pragma unroll
        for (int r = 0; r < 4; ++r) zred[((lc * 4 + r) * 16 + lr) * 4 + wv] = zacc[r];
        __syncthreads();
        float z = zred[tid * 4 + 0] + zred[tid * 4 + 1] + zred[tid * 4 + 2] + zred[tid * 4 + 3];
        int g = tid >> 4, i = tid & 15;
        Zout[(size_t)split * 65536 + (size_t)(b * 16 + g) * SEQ + it * 16 + i] = z;
    } else {
        f16* dst = Octx + (size_t)split * 4194304;
        #pragma unroll
        for (int gg = 0; gg < 4; ++gg)
            #pragma unroll
            for (int dt = 0; dt < 4; ++dt)
                #pragma unroll
                for (int r = 0; r < 4; ++r) {
                    int row = it * 16 + lc * 4 + r;
                    int col = (wv * 4 + gg) * 64 + dt * 16 + lr;
                    dst[(size_t)(b * SEQ + row) * DMODEL + col] = (f16)pv[gg][dt][r];
                }
    }
}

// ---------------------------------------------------------------------------
extern "C" void kernel_launch(void* const* d_in, const int* in_sizes, int n_in,
                              void* d_out, int out_size, void* d_ws, size_t ws_size,
                              hipStream_t stream)
{
    const float* x     = (const float*)d_in[0];
    const float* Wqkv  = (const float*)d_in[1];
    const float* bqkv  = (const float*)d_in[2];
    const float* Wpre  = (const float*)d_in[3];
    const float* Wpost = (const float*)d_in[4];
    const float* Wout  = (const float*)d_in[5];
    const float* bout  = (const float*)d_in[6];
    float* out = (float*)d_out;

    float* ws = (float*)d_ws;
    // float offsets (1M = 1048576). Total 19.25M floats = 77 MB.
    f16*   QKVh = (f16*)(ws);                  // [0, 6M floats) f16; dead after packs
    f16*   CTXp = (f16*)(ws);                  // [0, 8M floats) 4 x f16 partials (overlay)
    f16*   Xh   = (f16*)(ws + 8388608);        // [8M, 10M)
    f16*   Wqh  = (f16*)(ws + 10485760);       // [10M, 11.5M)
    f16*   Woh  = (f16*)(ws + 12058624);       // [11.5M, 12M)
    f16*   Qh   = (f16*)(ws + 12582912);       // [12M, 14M)
    f16*   Kh   = (f16*)(ws + 14680064);       // [14M, 16M)
    f16*   Vt   = (f16*)(ws + 16777216);       // [16M, 18M)
    f16*   Ch   = (f16*)(ws + 18874368);       // [18M, 19M)
    float* Zp   = ws + 19922944;               // [19M, +262144)

    dim3 blk(256);
    cvt_f16_kernel<<<4096, blk, 0, stream>>>(x, Wqkv, Wout, Xh, Wqh, Woh);
    gemm_f16_kernel<<<dim3(24, 32), blk, 0, stream>>>(Xh, Wqh, bqkv, (void*)QKVh, 3072, 1024, 0);
    pack_qk_kernel<<<2048, blk, 0, stream>>>(QKVh, Qh, Kh);
    pack_v_kernel<<<2048, blk, 0, stream>>>(QKVh, Vt);
    attn_core<0><<<1024, blk, 0, stream>>>(Qh, Kh, Vt, Wpre, Wpost, nullptr, Zp, nullptr);
    attn_core<1><<<1024, blk, 0, stream>>>(Qh, Kh, Vt, Wpre, Wpost, Zp, nullptr, CTXp);
    pack_ctx_kernel<<<2048, blk, 0, stream>>>(CTXp, Ch);
    gemm_f16_kernel<<<dim3(8, 32), blk, 0, stream>>>(Ch, Woh, bout, (void*)out, 1024, 1024, 1);
}

// Round 6
// 215.738 us; speedup vs baseline: 1.6005x; 1.6005x over previous
//
#include <hip/hip_runtime.h>
#include <cstddef>
#include <cstdint>

#define SEQ    2048
#define DMODEL 1024
#define NHEAD  16
#define HDIM   64
#define SCALE  0.125f

typedef _Float16 f16;
typedef unsigned short u16;
typedef unsigned int   u32;
typedef __attribute__((ext_vector_type(8))) _Float16 h8v;
typedef __attribute__((ext_vector_type(4))) _Float16 h4v;
typedef __attribute__((ext_vector_type(4))) float    f4v;

__device__ __forceinline__ u32 pkh(float a, float b) {
    u16 x = __builtin_bit_cast(u16, (f16)a);
    u16 y = __builtin_bit_cast(u16, (f16)b);
    return (u32)x | ((u32)y << 16);
}

__device__ __forceinline__ f4v mfma32(h8v a, h8v b, f4v c) {
    return __builtin_amdgcn_mfma_f32_16x16x32_f16(a, b, c, 0, 0, 0);
}
__device__ __forceinline__ f4v mfma16(h4v a, h4v b, f4v c) {
    return __builtin_amdgcn_mfma_f32_16x16x16f16(a, b, c, 0, 0, 0);
}

// ---------------------------------------------------------------------------
// Convert x, Wqkv, Wout (fp32) -> f16 row-major copies.
// ---------------------------------------------------------------------------
__global__ __launch_bounds__(256)
void cvt_f16_kernel(const float* __restrict__ x, const float* __restrict__ Wqkv,
                    const float* __restrict__ Wout,
                    f16* __restrict__ Xh, f16* __restrict__ Wqh, f16* __restrict__ Woh)
{
    size_t i = ((size_t)blockIdx.x * 256 + threadIdx.x) * 8;
    const float* src; f16* dst; size_t off;
    if (i < 4194304)      { src = x;    dst = Xh;  off = i; }
    else if (i < 7340032) { src = Wqkv; dst = Wqh; off = i - 4194304; }
    else                  { src = Wout; dst = Woh; off = i - 7340032; }
    float4 a = *(const float4*)&src[off];
    float4 b = *(const float4*)&src[off + 4];
    uint4 o;
    o.x = pkh(a.x, a.y); o.y = pkh(a.z, a.w);
    o.z = pkh(b.x, b.y); o.w = pkh(b.z, b.w);
    *(uint4*)&dst[off] = o;
}

// ---------------------------------------------------------------------------
// f16 MFMA GEMM: C = A @ B^T + bias. 128x128 tile, BK=32, 4 waves.
// mode 0: store f16. mode 1: store fp32.
// ---------------------------------------------------------------------------
__global__ __launch_bounds__(256)
void gemm_f16_kernel(const f16* __restrict__ A, const f16* __restrict__ B,
                     const float* __restrict__ bias, void* __restrict__ Cout,
                     int N, int K, int mode)
{
    __shared__ __align__(16) char Asb[8192];
    __shared__ __align__(16) char Bsb[8192];
    int tid = threadIdx.x;
    int w = tid >> 6, l = tid & 63, lr = l & 15, lc = l >> 4;
    int row0 = blockIdx.y * 128, col0 = blockIdx.x * 128;
    int wr = (w >> 1) * 64, wc = (w & 1) * 64;

    f4v acc[4][4];
    #pragma unroll
    for (int m = 0; m < 4; ++m)
        #pragma unroll
        for (int n = 0; n < 4; ++n) acc[m][n] = (f4v){0.f, 0.f, 0.f, 0.f};

    int r0 = tid >> 2, k0s = tid & 3;
    int r1 = (tid + 256) >> 2, k1s = tid & 3;

    uint4 ra0, ra1, rb0, rb1;
    ra0 = *(const uint4*)&A[(size_t)(row0 + r0) * K + k0s * 8];
    ra1 = *(const uint4*)&A[(size_t)(row0 + r1) * K + k1s * 8];
    rb0 = *(const uint4*)&B[(size_t)(col0 + r0) * K + k0s * 8];
    rb1 = *(const uint4*)&B[(size_t)(col0 + r1) * K + k1s * 8];

    int NT = K >> 5;
    for (int kt = 0; kt < NT; ++kt) {
        *(uint4*)(Asb + r0 * 64 + ((k0s ^ (r0 & 3)) << 4)) = ra0;
        *(uint4*)(Asb + r1 * 64 + ((k1s ^ (r1 & 3)) << 4)) = ra1;
        *(uint4*)(Bsb + r0 * 64 + ((k0s ^ (r0 & 3)) << 4)) = rb0;
        *(uint4*)(Bsb + r1 * 64 + ((k1s ^ (r1 & 3)) << 4)) = rb1;
        if (kt + 1 < NT) {
            int kk = (kt + 1) * 32;
            ra0 = *(const uint4*)&A[(size_t)(row0 + r0) * K + kk + k0s * 8];
            ra1 = *(const uint4*)&A[(size_t)(row0 + r1) * K + kk + k1s * 8];
            rb0 = *(const uint4*)&B[(size_t)(col0 + r0) * K + kk + k0s * 8];
            rb1 = *(const uint4*)&B[(size_t)(col0 + r1) * K + kk + k1s * 8];
        }
        __syncthreads();
        h8v af[4], bf[4];
        #pragma unroll
        for (int m = 0; m < 4; ++m) {
            int row = wr + m * 16 + lr;
            af[m] = *(h8v*)(Asb + row * 64 + ((lc ^ (row & 3)) << 4));
        }
        #pragma unroll
        for (int n = 0; n < 4; ++n) {
            int col = wc + n * 16 + lr;
            bf[n] = *(h8v*)(Bsb + col * 64 + ((lc ^ (col & 3)) << 4));
        }
        #pragma unroll
        for (int m = 0; m < 4; ++m)
            #pragma unroll
            for (int n = 0; n < 4; ++n)
                acc[m][n] = mfma32(af[m], bf[n], acc[m][n]);
        __syncthreads();
    }

    #pragma unroll
    for (int m = 0; m < 4; ++m)
        #pragma unroll
        for (int r = 0; r < 4; ++r) {
            int row = row0 + wr + m * 16 + lc * 4 + r;
            #pragma unroll
            for (int n = 0; n < 4; ++n) {
                int col = col0 + wc + n * 16 + lr;
                float v = acc[m][n][r] + bias[col];
                if (mode == 0) ((f16*)Cout)[(size_t)row * N + col] = (f16)v;
                else           ((float*)Cout)[(size_t)row * N + col] = v;
            }
        }
}

// ---------------------------------------------------------------------------
// Pack Q,K (with RoPE) from f16 QKV [row][3072] into f16 MFMA frag layout.
// ---------------------------------------------------------------------------
__global__ __launch_bounds__(256)
void pack_qk_kernel(const f16* __restrict__ QKVh, f16* __restrict__ Qh, f16* __restrict__ Kh)
{
    int gid = blockIdx.x * 256 + threadIdx.x;
    int i     = gid & 15;
    int t8    = (gid >> 4) & 3;
    int h     = (gid >> 6) & 15;
    int rh    = (gid >> 10) & 255;
    int which = (gid >> 18) & 1;
    int row = rh * 16 + i;
    int pos = row & (SEQ - 1);
    int b   = row >> 11;
    f16* dst = which ? Kh : Qh;

    h8v x1 = *(const h8v*)&QKVh[(size_t)row * 3072 + which * 1024 + h * 64 + t8 * 8];
    h8v x2 = *(const h8v*)&QKVh[(size_t)row * 3072 + which * 1024 + h * 64 + t8 * 8 + 32];

    float y1[8], y2[8];
    #pragma unroll
    for (int e = 0; e < 8; ++e) {
        int t = t8 * 8 + e;
        float inv = exp2f((float)(-2 * t) * (0.015625f * 13.287712379549449f));
        float ang = (float)pos * inv;
        float c, s;
        sincosf(ang, &s, &c);
        float a1 = (float)x1[e], a2 = (float)x2[e];
        y1[e] = a1 * c - a2 * s;
        y2[e] = a1 * s + a2 * c;
    }
    int it = pos >> 4;
    size_t b0 = (((((size_t)(b*128 + it)*16 + h)*2 + 0)*4 + t8)*16 + i)*8;
    size_t b1 = (((((size_t)(b*128 + it)*16 + h)*2 + 1)*4 + t8)*16 + i)*8;
    uint4 o0, o1;
    o0.x = pkh(y1[0], y1[1]); o0.y = pkh(y1[2], y1[3]);
    o0.z = pkh(y1[4], y1[5]); o0.w = pkh(y1[6], y1[7]);
    o1.x = pkh(y2[0], y2[1]); o1.y = pkh(y2[2], y2[3]);
    o1.z = pkh(y2[4], y2[5]); o1.w = pkh(y2[6], y2[7]);
    *(uint4*)(dst + b0) = o0;
    *(uint4*)(dst + b1) = o1;
}

// ---------------------------------------------------------------------------
// Pack V from f16 QKV [row][3072] (cols 2048..3071) into PV B-frag layout.
// ---------------------------------------------------------------------------
__global__ __launch_bounds__(256)
void pack_v_kernel(const f16* __restrict__ QKVh, f16* __restrict__ Vt)
{
    int gid = blockIdx.x * 256 + threadIdx.x;
    int dd = gid & 15;
    int jc = (gid >> 4) & 3;
    int dt = (gid >> 6) & 3;
    int g  = (gid >> 8) & 15;
    int jt = (gid >> 12) & 63;
    int b  = (gid >> 18) & 1;
    int d = g * 64 + dt * 16 + dd;
    f16 v[8];
    #pragma unroll
    for (int e = 0; e < 8; ++e) {
        int j = jt * 32 + jc * 8 + e;
        v[e] = QKVh[(size_t)(b * SEQ + j) * 3072 + 2048 + d];
    }
    size_t off = ((((((size_t)b*64 + jt)*16 + g)*4 + dt)*4 + jc)*16 + dd)*8;
    uint4 o;
    o.x = pkh((float)v[0], (float)v[1]); o.y = pkh((float)v[2], (float)v[3]);
    o.z = pkh((float)v[4], (float)v[5]); o.w = pkh((float)v[6], (float)v[7]);
    *(uint4*)(Vt + off) = o;
}

// ---------------------------------------------------------------------------
// Sum 2 f16 attention split partials -> f16 CTX [4096][1024].
// ---------------------------------------------------------------------------
__global__ __launch_bounds__(256)
void pack_ctx_kernel(const f16* __restrict__ Cp, f16* __restrict__ Ch)
{
    size_t i = ((size_t)blockIdx.x * 256 + threadIdx.x) * 8;
    h8v p0 = *(const h8v*)&Cp[i];
    h8v p1 = *(const h8v*)&Cp[i + 4194304];
    float s[8];
    #pragma unroll
    for (int e = 0; e < 8; ++e)
        s[e] = (float)p0[e] + (float)p1[e];
    uint4 o;
    o.x = pkh(s[0], s[1]); o.y = pkh(s[2], s[3]);
    o.z = pkh(s[4], s[5]); o.w = pkh(s[6], s[7]);
    *(uint4*)&Ch[i] = o;
}

// ---------------------------------------------------------------------------
// MFMA talking-heads attention core. 512 threads = 8 waves; wave wv owns
// heads {2wv,2wv+1} for QK^T and output heads {2wv,2wv+1} for PV.
// QBLK=32 (2 itiles of 16 rows). 2 splits of 1024 keys. kf double-buffered.
// Grid 256: bid = split*128 + b*64 + it2  (group in HIGH bits: chunked
// dispatch gives each XCD one (split,b)'s 4MB K+V working set).
// ---------------------------------------------------------------------------
template<int FULL>
__global__ __launch_bounds__(512, 2)
void attn_core(const f16* __restrict__ Qh, const f16* __restrict__ Kh,
               const f16* __restrict__ Vt, const float* __restrict__ Wpre,
               const float* __restrict__ Wpost, const float* __restrict__ Zp,
               float* __restrict__ Zout, f16* __restrict__ Octx)
{
    __shared__ __align__(16) char ss[2 * 16384];                  // S0 per itile
    __shared__ __align__(16) char es[FULL ? 2 * 16384 : 16];      // A2 per itile
    __shared__ float zred[FULL ? 512 : 4096];

    int tid = threadIdx.x;
    int wv = tid >> 6;          // 0..7
    int l  = tid & 63;
    int lr = l & 15;
    int lc = l >> 4;

    int bid   = blockIdx.x;
    int it2   = bid & 63;
    int b     = (bid >> 6) & 1;
    int split = bid >> 7;

    // Wpre fragment (A of 16x16x16): row g' = lr, k(h) = lc*4+e
    h4v wpre4;
    #pragma unroll
    for (int e = 0; e < 4; ++e) wpre4[e] = (f16)(Wpre[lr * 16 + lc * 4 + e] * SCALE);
    h4v wpost;
    if (FULL) {
        #pragma unroll
        for (int e = 0; e < 4; ++e) wpost[e] = (f16)Wpost[lr * 16 + lc * 4 + e];
    }

    // Q fragments: [itile][hh][ks]
    h8v qf[2][2][2];
    #pragma unroll
    for (int itl = 0; itl < 2; ++itl)
        #pragma unroll
        for (int hh = 0; hh < 2; ++hh)
            #pragma unroll
            for (int ks = 0; ks < 2; ++ks) {
                size_t off = ((((size_t)((b*128 + it2*2 + itl)*16 + (wv*2 + hh))*2 + ks)*4 + lc)*16 + lr)*8;
                qf[itl][hh][ks] = *(const h8v*)(Qh + off);
            }

    float zin4[2][4];
    float zacc[2][4] = {};
    if (FULL) {
        int itl = tid >> 8, g = (tid >> 4) & 15, i = tid & 15;
        size_t idx = (size_t)(b * 16 + g) * SEQ + it2 * 32 + itl * 16 + i;
        zred[tid] = 1.0f / (Zp[idx] + Zp[65536 + idx]);
        __syncthreads();
        #pragma unroll
        for (int itl2 = 0; itl2 < 2; ++itl2)
            #pragma unroll
            for (int r = 0; r < 4; ++r)
                zin4[itl2][r] = zred[itl2 * 256 + (lc * 4 + r) * 16 + lr];
    }

    f4v pv[2][2][4];   // [itile][gg][dt]
    if (FULL) {
        #pragma unroll
        for (int itl = 0; itl < 2; ++itl)
            #pragma unroll
            for (int gg = 0; gg < 2; ++gg)
                #pragma unroll
                for (int dt = 0; dt < 4; ++dt) pv[itl][gg][dt] = (f4v){0.f, 0.f, 0.f, 0.f};
    }

    int j0beg = split * 1024;
    int jtbeg = j0beg >> 4;

    h8v kfA[2][2][2], kfB[2][2][2];   // [hh][js][ks]
    // prologue: load step 0 into kfA
    #pragma unroll
    for (int hh = 0; hh < 2; ++hh)
        #pragma unroll
        for (int js = 0; js < 2; ++js)
            #pragma unroll
            for (int ks = 0; ks < 2; ++ks) {
                size_t off = ((((size_t)((b*128 + jtbeg + js)*16 + (wv*2 + hh))*2 + ks)*4 + lc)*16 + lr)*8;
                kfA[hh][js][ks] = *(const h8v*)(Kh + off);
            }

    auto step = [&](int s, h8v (&kfU)[2][2][2], h8v (&kfP)[2][2][2]) {
        int j0 = j0beg + s * 32;
        // ---- V loads for this step (FULL), consumed in phase 3 ----
        h8v vf[2][4];
        if (FULL) {
            #pragma unroll
            for (int gg = 0; gg < 2; ++gg)
                #pragma unroll
                for (int dt = 0; dt < 4; ++dt) {
                    size_t voff = (((((size_t)(b*64 + (j0 >> 5))*16 + (wv*2 + gg))*4 + dt)*4 + lc)*16 + lr)*8;
                    vf[gg][dt] = *(const h8v*)(Vt + voff);
                }
        }
        // ---- phase 1: QK^T for both itiles with kfU ----
        f4v qk[2][2][2];   // [itl][hh][js]
        #pragma unroll
        for (int itl = 0; itl < 2; ++itl)
            #pragma unroll
            for (int hh = 0; hh < 2; ++hh)
                #pragma unroll
                for (int js = 0; js < 2; ++js) {
                    f4v a = (f4v){0.f, 0.f, 0.f, 0.f};
                    a = mfma32(qf[itl][hh][0], kfU[hh][js][0], a);
                    a = mfma32(qf[itl][hh][1], kfU[hh][js][1], a);
                    qk[itl][hh][js] = a;
                }
        // ---- prefetch next step's K into kfP ----
        {
            int sp = (s + 1 < 32) ? (s + 1) : 0;
            int jt0 = jtbeg + sp * 2;
            #pragma unroll
            for (int hh = 0; hh < 2; ++hh)
                #pragma unroll
                for (int js = 0; js < 2; ++js)
                    #pragma unroll
                    for (int ks = 0; ks < 2; ++ks) {
                        size_t off = ((((size_t)((b*128 + jt0 + js)*16 + (wv*2 + hh))*2 + ks)*4 + lc)*16 + lr)*8;
                        kfP[hh][js][ks] = *(const h8v*)(Kh + off);
                    }
        }
        // ---- S0 -> ss: slot hs=wv>>1, half=wv&1 ----
        #pragma unroll
        for (int itl = 0; itl < 2; ++itl)
            #pragma unroll
            for (int js = 0; js < 2; ++js)
                #pragma unroll
                for (int r = 0; r < 4; ++r) {
                    int i = lc * 4 + r;
                    int addr = itl * 16384 + ((wv >> 1) * 2 + js) * 2048 + i * 128
                             + ((lr ^ i) << 3) + (wv & 1) * 4;
                    *(u32*)(ss + addr) = pkh(qk[itl][0][js][r], qk[itl][1][js][r]);
                }
        __syncthreads();

        // ---- phase 2: premix -> exp -> (Z | /Z -> postmix -> es) ----
        u32 a2p[2][4][2];
        #pragma unroll
        for (int itl = 0; itl < 2; ++itl)
            #pragma unroll
            for (int tt = 0; tt < 4; ++tt) {
                int t = wv * 4 + tt;
                int addr = itl * 16384 + (lc * 2 + (t >> 4)) * 2048 + lr * 128
                         + (((t & 15) ^ lr) << 3);
                union { uint2 u; h4v v; } cv;
                cv.u = *(uint2*)(ss + addr);
                f4v s1 = mfma16(wpre4, cv.v, (f4v){0.f, 0.f, 0.f, 0.f});
                if (!FULL) {
                    #pragma unroll
                    for (int r = 0; r < 4; ++r) zacc[itl][r] += __expf(s1[r]);
                } else {
                    h4v pf;
                    #pragma unroll
                    for (int r = 0; r < 4; ++r) pf[r] = (f16)(__expf(s1[r]) * zin4[itl][r]);
                    f4v a2 = mfma16(wpost, pf, (f4v){0.f, 0.f, 0.f, 0.f});
                    #pragma unroll
                    for (int r = 0; r < 4; ++r) {
                        u32 v = (u32)__builtin_bit_cast(u16, (f16)a2[r]);
                        if (tt & 1) a2p[itl][r][tt >> 1] |= v << 16;
                        else        a2p[itl][r][tt >> 1]  = v;
                    }
                }
            }
        if (FULL) {
            #pragma unroll
            for (int itl = 0; itl < 2; ++itl)
                #pragma unroll
                for (int r = 0; r < 4; ++r) {
                    int gq = lc * 4 + r;
                    int off = itl * 16384 + ((gq * 1024 + lr * 64 + wv * 8) ^ ((lr & 7) << 4));
                    *(uint2*)(es + off) = make_uint2(a2p[itl][r][0], a2p[itl][r][1]);
                }
        }
        __syncthreads();

        // ---- phase 3: PV ----
        if (FULL) {
            #pragma unroll
            for (int gg = 0; gg < 2; ++gg) {
                int g = wv * 2 + gg;
                #pragma unroll
                for (int itl = 0; itl < 2; ++itl) {
                    h8v af = *(h8v*)(es + itl * 16384
                                     + ((g * 1024 + lr * 64 + lc * 16) ^ ((lr & 7) << 4)));
                    #pragma unroll
                    for (int dt = 0; dt < 4; ++dt)
                        pv[itl][gg][dt] = mfma32(af, vf[gg][dt], pv[itl][gg][dt]);
                }
            }
        }
    };

    for (int s = 0; s < 32; s += 2) {
        step(s,     kfA, kfB);
        step(s + 1, kfB, kfA);
    }

    if (!FULL) {
        #pragma unroll
        for (int itl = 0; itl < 2; ++itl)
            #pragma unroll
            for (int r = 0; r < 4; ++r)
                zred[itl * 2048 + ((lc * 4 + r) * 16 + lr) * 8 + wv] = zacc[itl][r];
        __syncthreads();
        int itl = tid >> 8, gi = tid & 255;
        float z = 0.f;
        #pragma unroll
        for (int w2 = 0; w2 < 8; ++w2) z += zred[itl * 2048 + gi * 8 + w2];
        int g = gi >> 4, i = gi & 15;
        Zout[(size_t)split * 65536 + (size_t)(b * 16 + g) * SEQ + it2 * 32 + itl * 16 + i] = z;
    } else {
        f16* dst = Octx + (size_t)split * 4194304;
        #pragma unroll
        for (int itl = 0; itl < 2; ++itl)
            #pragma unroll
            for (int gg = 0; gg < 2; ++gg)
                #pragma unroll
                for (int dt = 0; dt < 4; ++dt)
                    #pragma unroll
                    for (int r = 0; r < 4; ++r) {
                        int row = it2 * 32 + itl * 16 + lc * 4 + r;
                        int col = (wv * 2 + gg) * 64 + dt * 16 + lr;
                        dst[(size_t)(b * SEQ + row) * DMODEL + col] = (f16)pv[itl][gg][dt][r];
                    }
    }
}

// ---------------------------------------------------------------------------
extern "C" void kernel_launch(void* const* d_in, const int* in_sizes, int n_in,
                              void* d_out, int out_size, void* d_ws, size_t ws_size,
                              hipStream_t stream)
{
    const float* x     = (const float*)d_in[0];
    const float* Wqkv  = (const float*)d_in[1];
    const float* bqkv  = (const float*)d_in[2];
    const float* Wpre  = (const float*)d_in[3];
    const float* Wpost = (const float*)d_in[4];
    const float* Wout  = (const float*)d_in[5];
    const float* bout  = (const float*)d_in[6];
    float* out = (float*)d_out;

    float* ws = (float*)d_ws;
    f16*   QKVh = (f16*)(ws);                  // [0, 6M floats) f16; dead after packs
    f16*   CTXp = (f16*)(ws);                  // [0, 4M floats) 2 x f16 partials (overlay)
    f16*   Xh   = (f16*)(ws + 8388608);
    f16*   Wqh  = (f16*)(ws + 10485760);
    f16*   Woh  = (f16*)(ws + 12058624);
    f16*   Qh   = (f16*)(ws + 12582912);
    f16*   Kh   = (f16*)(ws + 14680064);
    f16*   Vt   = (f16*)(ws + 16777216);
    f16*   Ch   = (f16*)(ws + 18874368);
    float* Zp   = ws + 19922944;               // 2 x 65536 floats

    dim3 blk(256);
    cvt_f16_kernel<<<4096, blk, 0, stream>>>(x, Wqkv, Wout, Xh, Wqh, Woh);
    gemm_f16_kernel<<<dim3(24, 32), blk, 0, stream>>>(Xh, Wqh, bqkv, (void*)QKVh, 3072, 1024, 0);
    pack_qk_kernel<<<2048, blk, 0, stream>>>(QKVh, Qh, Kh);
    pack_v_kernel<<<2048, blk, 0, stream>>>(QKVh, Vt);
    attn_core<0><<<256, dim3(512), 0, stream>>>(Qh, Kh, Vt, Wpre, Wpost, nullptr, Zp, nullptr);
    attn_core<1><<<256, dim3(512), 0, stream>>>(Qh, Kh, Vt, Wpre, Wpost, Zp, nullptr, CTXp);
    pack_ctx_kernel<<<2048, blk, 0, stream>>>(CTXp, Ch);
    gemm_f16_kernel<<<dim3(8, 32), blk, 0, stream>>>(Ch, Woh, bout, (void*)out, 1024, 1024, 1);
}